// Round 1
// baseline (1355.739 us; speedup 1.0000x reference)
//
#include <hip/hip_runtime.h>
#include <hip/hip_bf16.h>

#define NN 50000
#define EE 640000
#define LN_EPS 1e-5f

typedef __bf16 bf16x8 __attribute__((ext_vector_type(8)));
typedef float f32x4 __attribute__((ext_vector_type(4)));

static __device__ __forceinline__ unsigned short f2bf(float f) {
    return __builtin_bit_cast(unsigned short, (__bf16)f);
}

// ---- K0: weight prep: W1T[c][k]=bf16(W1[k][c]) (512x256), W2T[c][k]=bf16(W2[k][c]) (128x512)
__global__ __launch_bounds__(256) void prep_weights(const float* __restrict__ W1,
                                                    const float* __restrict__ W2,
                                                    unsigned short* __restrict__ W1T,
                                                    unsigned short* __restrict__ W2T) {
    int idx = blockIdx.x * 256 + threadIdx.x;
    if (idx < 131072) {            // 512 cols x 256 k
        int c = idx >> 8, k = idx & 255;
        W1T[idx] = f2bf(W1[k * 512 + c]);
    } else {                       // 128 cols x 512 k
        int j = idx - 131072;
        int c = j >> 9, k = j & 511;
        W2T[j] = f2bf(W2[k * 128 + c]);
    }
}

// ---- K1: edge scatter. 32 lanes per edge, float4 per lane.
__global__ __launch_bounds__(256) void scatter_kernel(const float* __restrict__ x,
                                                      const int* __restrict__ ei,
                                                      const float* __restrict__ edist,
                                                      float* __restrict__ agg,
                                                      float* __restrict__ dist_sum) {
    long long t = (long long)blockIdx.x * 256 + threadIdx.x;
    int e = (int)(t >> 5);
    int l = (int)(t & 31);
    if (e >= EE) return;
    int s = ei[e];            // src
    int d = ei[EE + e];       // dst
    f32x4 v = *(const f32x4*)(x + (size_t)d * 128 + l * 4);
    float* ap = agg + (size_t)s * 128 + l * 4;
    atomicAdd(ap + 0, v.x);
    atomicAdd(ap + 1, v.y);
    atomicAdd(ap + 2, v.z);
    atomicAdd(ap + 3, v.w);
    if (l == 0) atomicAdd(dist_sum + s, edist[e]);
}

// ---- K2: build featbf [N][256] bf16 = [x | agg/degc]; dist_md[i] := dist_sum[i]/degc (in place)
__global__ __launch_bounds__(256) void feat_kernel(const float* __restrict__ x,
                                                   const float* __restrict__ agg,
                                                   const float* __restrict__ degrees,
                                                   float* __restrict__ dist_md,
                                                   unsigned short* __restrict__ featbf) {
    int t = blockIdx.x * 256 + threadIdx.x;
    int node = t >> 5, part = t & 31;
    if (node >= NN) return;
    float degc = fmaxf(degrees[node], 1.0f);
    if (part == 0) dist_md[node] = dist_md[node] / degc;
    const float* srcp;
    float scale;
    int outc;
    if (part < 16) { srcp = x + (size_t)node * 128 + part * 8;          scale = 1.0f;        outc = part * 8; }
    else           { srcp = agg + (size_t)node * 128 + (part - 16) * 8; scale = 1.0f / degc; outc = 128 + (part - 16) * 8; }
    unsigned short o[8];
#pragma unroll
    for (int i = 0; i < 8; i++) o[i] = f2bf(srcp[i] * scale);
    *(uint4*)(featbf + (size_t)node * 256 + outc) = *(const uint4*)o;
}

// ---- K3: GEMM1: h = relu(feat @ W1[0:256] + deg*W1[256] + md*W1[257] + b1), bf16 out [N][512]
__global__ __launch_bounds__(256) void gemm1_kernel(const unsigned short* __restrict__ featbf,
                                                    const unsigned short* __restrict__ W1T,
                                                    const float* __restrict__ W1,
                                                    const float* __restrict__ b1,
                                                    const float* __restrict__ degrees,
                                                    const float* __restrict__ md,
                                                    unsigned short* __restrict__ h) {
    __shared__ __align__(16) unsigned char lds[65536];
    unsigned char* Af = lds;           // 64 rows x 256 k bf16, XOR-swizzled
    unsigned char* Bf = lds + 32768;   // 64 cols x 256 k bf16, XOR-swizzled
    int tid = threadIdx.x;
    int r0 = blockIdx.x * 64;
    int c0 = blockIdx.y * 64;

    for (int idx = tid; idx < 2048; idx += 256) {       // stage A (feat rows)
        int row = idx >> 5, ck = idx & 31;
        int gr = r0 + row;
        uint4 v = make_uint4(0, 0, 0, 0);
        if (gr < NN) v = *(const uint4*)(featbf + (size_t)gr * 256 + ck * 8);
        *(uint4*)(Af + (((row << 9) + (ck << 4)) ^ ((row & 7) << 4))) = v;
    }
    for (int idx = tid; idx < 2048; idx += 256) {       // stage B (W1T cols)
        int col = idx >> 5, ck = idx & 31;
        uint4 v = *(const uint4*)(W1T + (size_t)(c0 + col) * 256 + ck * 8);
        *(uint4*)(Bf + (((col << 9) + (ck << 4)) ^ ((col & 7) << 4))) = v;
    }
    __syncthreads();

    int wave = tid >> 6, lane = tid & 63;
    int wm = wave >> 1, wn = wave & 1;
    int lr = lane & 15, lg = lane >> 4;
    f32x4 acc[2][2] = {};
#pragma unroll
    for (int ks = 0; ks < 8; ks++) {
        bf16x8 a[2], b[2];
#pragma unroll
        for (int i = 0; i < 2; i++) {
            int row = wm * 32 + i * 16 + lr;
            a[i] = *(const bf16x8*)(Af + (((row << 9) + (ks << 6) + (lg << 4)) ^ ((row & 7) << 4)));
            int col = wn * 32 + i * 16 + lr;
            b[i] = *(const bf16x8*)(Bf + (((col << 9) + (ks << 6) + (lg << 4)) ^ ((col & 7) << 4)));
        }
#pragma unroll
        for (int i = 0; i < 2; i++)
#pragma unroll
            for (int j = 0; j < 2; j++)
                acc[i][j] = __builtin_amdgcn_mfma_f32_16x16x32_bf16(a[i], b[j], acc[i][j], 0, 0, 0);
    }

    const float* wdeg = W1 + 256 * 512;
    const float* wmd  = W1 + 257 * 512;
#pragma unroll
    for (int i = 0; i < 2; i++) {
#pragma unroll
        for (int reg = 0; reg < 4; reg++) {
            int gr = r0 + wm * 32 + i * 16 + lg * 4 + reg;
            if (gr >= NN) continue;
            float dg = degrees[gr], m = md[gr];
#pragma unroll
            for (int j = 0; j < 2; j++) {
                int gc = c0 + wn * 32 + j * 16 + lr;
                float v = acc[i][j][reg] + dg * wdeg[gc] + m * wmd[gc] + b1[gc];
                v = fmaxf(v, 0.0f);
                h[(size_t)gr * 512 + gc] = f2bf(v);
            }
        }
    }
}

// ---- K4: GEMM2 (h @ W2 + b2) + residual + LayerNorm, fused.
__global__ __launch_bounds__(256) void gemm2_ln_kernel(const unsigned short* __restrict__ h,
                                                       const unsigned short* __restrict__ W2T,
                                                       const float* __restrict__ x,
                                                       const float* __restrict__ b2,
                                                       const float* __restrict__ gamma,
                                                       const float* __restrict__ beta,
                                                       float* __restrict__ out) {
    __shared__ __align__(16) unsigned char lds[49152];
    unsigned char* Af = lds;            // 64 rows x 128 k bf16
    unsigned char* Bf = lds + 16384;    // 128 cols x 128 k bf16
    float* ytile = (float*)lds;         // 64 x 132 fp32 (reuses staging LDS)
    int tid = threadIdx.x;
    int r0 = blockIdx.x * 64;
    int wave = tid >> 6, lane = tid & 63;
    int wm = wave >> 1, wn = wave & 1;
    int lr = lane & 15, lg = lane >> 4;
    f32x4 acc[2][4] = {};

    for (int kt = 0; kt < 4; kt++) {
        if (kt) __syncthreads();
        for (int idx = tid; idx < 1024; idx += 256) {   // stage A (h rows)
            int row = idx >> 4, ck = idx & 15;
            int gr = r0 + row;
            uint4 v = make_uint4(0, 0, 0, 0);
            if (gr < NN) v = *(const uint4*)(h + (size_t)gr * 512 + kt * 128 + ck * 8);
            *(uint4*)(Af + (((row << 8) + (ck << 4)) ^ ((row & 7) << 4))) = v;
        }
        for (int idx = tid; idx < 2048; idx += 256) {   // stage B (W2T cols)
            int col = idx >> 4, ck = idx & 15;
            uint4 v = *(const uint4*)(W2T + (size_t)col * 512 + kt * 128 + ck * 8);
            *(uint4*)(Bf + (((col << 8) + (ck << 4)) ^ ((col & 7) << 4))) = v;
        }
        __syncthreads();
#pragma unroll
        for (int ks = 0; ks < 4; ks++) {
            bf16x8 a[2], b[4];
#pragma unroll
            for (int i = 0; i < 2; i++) {
                int row = wm * 32 + i * 16 + lr;
                a[i] = *(const bf16x8*)(Af + (((row << 8) + (ks << 6) + (lg << 4)) ^ ((row & 7) << 4)));
            }
#pragma unroll
            for (int j = 0; j < 4; j++) {
                int col = wn * 64 + j * 16 + lr;
                b[j] = *(const bf16x8*)(Bf + (((col << 8) + (ks << 6) + (lg << 4)) ^ ((col & 7) << 4)));
            }
#pragma unroll
            for (int i = 0; i < 2; i++)
#pragma unroll
                for (int j = 0; j < 4; j++)
                    acc[i][j] = __builtin_amdgcn_mfma_f32_16x16x32_bf16(a[i], b[j], acc[i][j], 0, 0, 0);
        }
    }
    __syncthreads();   // staging LDS dead; reuse as ytile

    // y = acc + b2 + x  -> ytile
#pragma unroll
    for (int i = 0; i < 2; i++) {
#pragma unroll
        for (int reg = 0; reg < 4; reg++) {
            int rl = wm * 32 + i * 16 + lg * 4 + reg;
            int gr = r0 + rl;
#pragma unroll
            for (int j = 0; j < 4; j++) {
                int gc = wn * 64 + j * 16 + lr;
                float v = acc[i][j][reg] + b2[gc];
                if (gr < NN) v += x[(size_t)gr * 128 + gc];
                ytile[rl * 132 + gc] = v;
            }
        }
    }
    __syncthreads();

    // LayerNorm: 4 threads per row, 32 elems each (strided col = p + 4q)
    int r = tid >> 2, p = tid & 3;
    int gr = r0 + r;
    float sum = 0.f, sq = 0.f;
    float vals[32];
#pragma unroll
    for (int q = 0; q < 32; q++) {
        float v = ytile[r * 132 + p + 4 * q];
        vals[q] = v;
        sum += v;
        sq += v * v;
    }
    sum += __shfl_xor(sum, 1, 64); sq += __shfl_xor(sq, 1, 64);
    sum += __shfl_xor(sum, 2, 64); sq += __shfl_xor(sq, 2, 64);
    float mu = sum * (1.0f / 128.0f);
    float var = sq * (1.0f / 128.0f) - mu * mu;
    float rs = rsqrtf(var + LN_EPS);
    if (gr < NN) {
#pragma unroll
        for (int q = 0; q < 32; q++) {
            int col = p + 4 * q;
            out[(size_t)gr * 128 + col] = (vals[q] - mu) * rs * gamma[col] + beta[col];
        }
    }
}

extern "C" void kernel_launch(void* const* d_in, const int* in_sizes, int n_in,
                              void* d_out, int out_size, void* d_ws, size_t ws_size,
                              hipStream_t stream) {
    const float* x       = (const float*)d_in[0];
    const float* W1      = (const float*)d_in[1];
    const float* b1      = (const float*)d_in[2];
    const float* W2      = (const float*)d_in[3];
    const float* b2      = (const float*)d_in[4];
    const float* gamma   = (const float*)d_in[5];
    const float* beta    = (const float*)d_in[6];
    const int*   ei      = (const int*)d_in[7];
    const float* edist   = (const float*)d_in[8];
    const float* degrees = (const float*)d_in[9];
    float* out = (float*)d_out;

    char* ws = (char*)d_ws;
    size_t off = 0;
    auto alloc = [&](size_t bytes) {
        void* p = ws + off;
        off = (off + bytes + 255) & ~(size_t)255;
        return p;
    };
    float* agg              = (float*)alloc((size_t)NN * 128 * 4);  // 25.6 MB
    float* dist_md          = (float*)alloc((size_t)NN * 4);        // dist_sum, becomes mean_dist
    unsigned short* featbf  = (unsigned short*)alloc((size_t)NN * 256 * 2);
    unsigned short* W1T     = (unsigned short*)alloc(512 * 256 * 2);
    unsigned short* W2T     = (unsigned short*)alloc(128 * 512 * 2);
    unsigned short* h       = (unsigned short*)alloc((size_t)NN * 512 * 2);

    // agg and dist_md are contiguous (agg size is 256B-aligned): one memset
    hipMemsetAsync(agg, 0, (size_t)NN * 128 * 4 + (size_t)NN * 4, stream);

    prep_weights<<<768, 256, 0, stream>>>(W1, W2, W1T, W2T);
    scatter_kernel<<<(EE * 32) / 256, 256, 0, stream>>>(x, ei, edist, agg, dist_md);
    feat_kernel<<<(NN * 32 + 255) / 256, 256, 0, stream>>>(x, agg, degrees, dist_md, featbf);
    gemm1_kernel<<<dim3((NN + 63) / 64, 8), 256, 0, stream>>>(featbf, W1T, W1, b1, degrees, dist_md, h);
    gemm2_ln_kernel<<<(NN + 63) / 64, 256, 0, stream>>>(h, W2T, x, b2, gamma, beta, out);
}

// Round 2
// 350.357 us; speedup vs baseline: 3.8696x; 3.8696x over previous
//
#include <hip/hip_runtime.h>
#include <hip/hip_bf16.h>

#define NN 50000
#define EE 640000
#define LN_EPS 1e-5f

typedef __bf16 bf16x8 __attribute__((ext_vector_type(8)));
typedef float f32x4 __attribute__((ext_vector_type(4)));

static __device__ __forceinline__ unsigned short f2bf(float f) {
    return __builtin_bit_cast(unsigned short, (__bf16)f);
}

// ---- K0: weight prep: W1T[c][k]=bf16(W1[k][c]) (512x256), W2T[c][k]=bf16(W2[k][c]) (128x512)
__global__ __launch_bounds__(256) void prep_weights(const float* __restrict__ W1,
                                                    const float* __restrict__ W2,
                                                    unsigned short* __restrict__ W1T,
                                                    unsigned short* __restrict__ W2T) {
    int idx = blockIdx.x * 256 + threadIdx.x;
    if (idx < 131072) {            // 512 cols x 256 k
        int c = idx >> 8, k = idx & 255;
        W1T[idx] = f2bf(W1[k * 512 + c]);
    } else {                       // 128 cols x 512 k
        int j = idx - 131072;
        int c = j >> 9, k = j & 511;
        W2T[j] = f2bf(W2[k * 128 + c]);
    }
}

// ---- Prefix scan of int(degrees) over NN elements: 3 tiny kernels ----
__global__ __launch_bounds__(256) void scanA(const float* __restrict__ degrees,
                                             int* __restrict__ blocksum) {
    __shared__ int wsum[4];
    int i = blockIdx.x * 256 + threadIdx.x;
    int v = (i < NN) ? (int)(degrees[i] + 0.5f) : 0;
    int s = v;
    for (int d = 1; d < 64; d <<= 1) s += __shfl_xor(s, d, 64);
    if ((threadIdx.x & 63) == 0) wsum[threadIdx.x >> 6] = s;
    __syncthreads();
    if (threadIdx.x == 0) blocksum[blockIdx.x] = wsum[0] + wsum[1] + wsum[2] + wsum[3];
}

__global__ __launch_bounds__(256) void scanB(const int* __restrict__ blocksum,
                                             int* __restrict__ blockoff, int nb) {
    __shared__ int wsum[4];
    int tid = threadIdx.x;
    int v = (tid < nb) ? blocksum[tid] : 0;
    int lane = tid & 63, wid = tid >> 6;
    int inc = v;
    for (int d = 1; d < 64; d <<= 1) { int t = __shfl_up(inc, d, 64); if (lane >= d) inc += t; }
    if (lane == 63) wsum[wid] = inc;
    __syncthreads();
    int add = 0;
    for (int w = 0; w < wid; w++) add += wsum[w];
    inc += add;
    if (tid < nb) blockoff[tid] = inc - v;   // exclusive
}

__global__ __launch_bounds__(256) void scanC(const float* __restrict__ degrees,
                                             const int* __restrict__ blockoff,
                                             int* __restrict__ start,
                                             int* __restrict__ cursor) {
    __shared__ int wsum[4];
    int tid = threadIdx.x;
    int i = blockIdx.x * 256 + tid;
    int v = (i < NN) ? (int)(degrees[i] + 0.5f) : 0;
    int lane = tid & 63, wid = tid >> 6;
    int inc = v;
    for (int d = 1; d < 64; d <<= 1) { int t = __shfl_up(inc, d, 64); if (lane >= d) inc += t; }
    if (lane == 63) wsum[wid] = inc;
    __syncthreads();
    int add = blockoff[blockIdx.x];
    for (int w = 0; w < wid; w++) add += wsum[w];
    int excl = add + inc - v;
    if (i < NN) { start[i] = excl; cursor[i] = excl; }
}

// ---- K_sort: bucket edges by src into CSR order; accumulate dist_sum (small atomics)
__global__ __launch_bounds__(256) void sort_kernel(const int* __restrict__ ei,
                                                   const float* __restrict__ edist,
                                                   int* __restrict__ cursor,
                                                   int* __restrict__ sorted_dst,
                                                   float* __restrict__ dist_sum) {
    int e = blockIdx.x * 256 + threadIdx.x;
    if (e >= EE) return;
    int s = ei[e];
    int d = ei[EE + e];
    int p = atomicAdd(cursor + s, 1);
    sorted_dst[p] = d;
    atomicAdd(dist_sum + s, edist[e]);
}

// ---- K_aggfeat: wave-per-node register aggregation + bf16 feat emit.
// featbf[node][0:128] = bf16(x[node]); featbf[node][128:256] = bf16(agg/degc);
// dist[node] := dist[node]/degc (in place -> mean_dist)
__global__ __launch_bounds__(256) void aggfeat_kernel(const float* __restrict__ x,
                                                      const int* __restrict__ start,
                                                      const float* __restrict__ degrees,
                                                      const int* __restrict__ sorted_dst,
                                                      float* __restrict__ dist,
                                                      unsigned short* __restrict__ featbf) {
    int tid = threadIdx.x;
    int node = blockIdx.x * 4 + (tid >> 6);
    int lane = tid & 63;
    if (node >= NN) return;
    int st = start[node];
    int cnt = (int)(degrees[node] + 0.5f);
    float a0 = 0.f, a1 = 0.f;
    for (int base = 0; base < cnt; base += 64) {
        int rem = cnt - base;
        int nv = rem < 64 ? rem : 64;
        int didx = 0;
        if (lane < nv) didx = sorted_dst[st + base + lane];
        int j = 0;
        for (; j + 4 <= nv; j += 4) {
            int d0 = __shfl(didx, j,     64);
            int d1 = __shfl(didx, j + 1, 64);
            int d2 = __shfl(didx, j + 2, 64);
            int d3 = __shfl(didx, j + 3, 64);
            float2 v0 = *((const float2*)(x + (size_t)d0 * 128) + lane);
            float2 v1 = *((const float2*)(x + (size_t)d1 * 128) + lane);
            float2 v2 = *((const float2*)(x + (size_t)d2 * 128) + lane);
            float2 v3 = *((const float2*)(x + (size_t)d3 * 128) + lane);
            a0 += v0.x + v1.x + v2.x + v3.x;
            a1 += v0.y + v1.y + v2.y + v3.y;
        }
        for (; j < nv; j++) {
            int dj = __shfl(didx, j, 64);
            float2 v = *((const float2*)(x + (size_t)dj * 128) + lane);
            a0 += v.x;
            a1 += v.y;
        }
    }
    float degc = fmaxf(degrees[node], 1.0f);
    float inv = 1.0f / degc;
    float2 xv = *((const float2*)(x + (size_t)node * 128) + lane);
    unsigned short o[4] = { f2bf(xv.x), f2bf(xv.y), f2bf(a0 * inv), f2bf(a1 * inv) };
    unsigned short* row = featbf + (size_t)node * 256;
    *(unsigned int*)(row + lane * 2)       = *(unsigned int*)&o[0];
    *(unsigned int*)(row + 128 + lane * 2) = *(unsigned int*)&o[2];
    if (lane == 0) dist[node] = dist[node] * inv;
}

// ---- K3: GEMM1: h = relu(feat @ W1[0:256] + deg*W1[256] + md*W1[257] + b1), bf16 out [N][512]
__global__ __launch_bounds__(256) void gemm1_kernel(const unsigned short* __restrict__ featbf,
                                                    const unsigned short* __restrict__ W1T,
                                                    const float* __restrict__ W1,
                                                    const float* __restrict__ b1,
                                                    const float* __restrict__ degrees,
                                                    const float* __restrict__ md,
                                                    unsigned short* __restrict__ h) {
    __shared__ __align__(16) unsigned char lds[65536];
    unsigned char* Af = lds;           // 64 rows x 256 k bf16, XOR-swizzled
    unsigned char* Bf = lds + 32768;   // 64 cols x 256 k bf16, XOR-swizzled
    int tid = threadIdx.x;
    int r0 = blockIdx.x * 64;
    int c0 = blockIdx.y * 64;

    for (int idx = tid; idx < 2048; idx += 256) {       // stage A (feat rows)
        int row = idx >> 5, ck = idx & 31;
        int gr = r0 + row;
        uint4 v = make_uint4(0, 0, 0, 0);
        if (gr < NN) v = *(const uint4*)(featbf + (size_t)gr * 256 + ck * 8);
        *(uint4*)(Af + (((row << 9) + (ck << 4)) ^ ((row & 7) << 4))) = v;
    }
    for (int idx = tid; idx < 2048; idx += 256) {       // stage B (W1T cols)
        int col = idx >> 5, ck = idx & 31;
        uint4 v = *(const uint4*)(W1T + (size_t)(c0 + col) * 256 + ck * 8);
        *(uint4*)(Bf + (((col << 9) + (ck << 4)) ^ ((col & 7) << 4))) = v;
    }
    __syncthreads();

    int wave = tid >> 6, lane = tid & 63;
    int wm = wave >> 1, wn = wave & 1;
    int lr = lane & 15, lg = lane >> 4;
    f32x4 acc[2][2] = {};
#pragma unroll
    for (int ks = 0; ks < 8; ks++) {
        bf16x8 a[2], b[2];
#pragma unroll
        for (int i = 0; i < 2; i++) {
            int row = wm * 32 + i * 16 + lr;
            a[i] = *(const bf16x8*)(Af + (((row << 9) + (ks << 6) + (lg << 4)) ^ ((row & 7) << 4)));
            int col = wn * 32 + i * 16 + lr;
            b[i] = *(const bf16x8*)(Bf + (((col << 9) + (ks << 6) + (lg << 4)) ^ ((col & 7) << 4)));
        }
#pragma unroll
        for (int i = 0; i < 2; i++)
#pragma unroll
            for (int j = 0; j < 2; j++)
                acc[i][j] = __builtin_amdgcn_mfma_f32_16x16x32_bf16(a[i], b[j], acc[i][j], 0, 0, 0);
    }

    const float* wdeg = W1 + 256 * 512;
    const float* wmd  = W1 + 257 * 512;
#pragma unroll
    for (int i = 0; i < 2; i++) {
#pragma unroll
        for (int reg = 0; reg < 4; reg++) {
            int gr = r0 + wm * 32 + i * 16 + lg * 4 + reg;
            if (gr >= NN) continue;
            float dg = degrees[gr], m = md[gr];
#pragma unroll
            for (int j = 0; j < 2; j++) {
                int gc = c0 + wn * 32 + j * 16 + lr;
                float v = acc[i][j][reg] + dg * wdeg[gc] + m * wmd[gc] + b1[gc];
                v = fmaxf(v, 0.0f);
                h[(size_t)gr * 512 + gc] = f2bf(v);
            }
        }
    }
}

// ---- K4: GEMM2 (h @ W2 + b2) + residual + LayerNorm, fused.
__global__ __launch_bounds__(256) void gemm2_ln_kernel(const unsigned short* __restrict__ h,
                                                       const unsigned short* __restrict__ W2T,
                                                       const float* __restrict__ x,
                                                       const float* __restrict__ b2,
                                                       const float* __restrict__ gamma,
                                                       const float* __restrict__ beta,
                                                       float* __restrict__ out) {
    __shared__ __align__(16) unsigned char lds[49152];
    unsigned char* Af = lds;            // 64 rows x 128 k bf16
    unsigned char* Bf = lds + 16384;    // 128 cols x 128 k bf16
    float* ytile = (float*)lds;         // 64 x 132 fp32 (reuses staging LDS)
    int tid = threadIdx.x;
    int r0 = blockIdx.x * 64;
    int wave = tid >> 6, lane = tid & 63;
    int wm = wave >> 1, wn = wave & 1;
    int lr = lane & 15, lg = lane >> 4;
    f32x4 acc[2][4] = {};

    for (int kt = 0; kt < 4; kt++) {
        if (kt) __syncthreads();
        for (int idx = tid; idx < 1024; idx += 256) {   // stage A (h rows)
            int row = idx >> 4, ck = idx & 15;
            int gr = r0 + row;
            uint4 v = make_uint4(0, 0, 0, 0);
            if (gr < NN) v = *(const uint4*)(h + (size_t)gr * 512 + kt * 128 + ck * 8);
            *(uint4*)(Af + (((row << 8) + (ck << 4)) ^ ((row & 7) << 4))) = v;
        }
        for (int idx = tid; idx < 2048; idx += 256) {   // stage B (W2T cols)
            int col = idx >> 4, ck = idx & 15;
            uint4 v = *(const uint4*)(W2T + (size_t)col * 512 + kt * 128 + ck * 8);
            *(uint4*)(Bf + (((col << 8) + (ck << 4)) ^ ((col & 7) << 4))) = v;
        }
        __syncthreads();
#pragma unroll
        for (int ks = 0; ks < 4; ks++) {
            bf16x8 a[2], b[4];
#pragma unroll
            for (int i = 0; i < 2; i++) {
                int row = wm * 32 + i * 16 + lr;
                a[i] = *(const bf16x8*)(Af + (((row << 8) + (ks << 6) + (lg << 4)) ^ ((row & 7) << 4)));
            }
#pragma unroll
            for (int j = 0; j < 4; j++) {
                int col = wn * 64 + j * 16 + lr;
                b[j] = *(const bf16x8*)(Bf + (((col << 8) + (ks << 6) + (lg << 4)) ^ ((col & 7) << 4)));
            }
#pragma unroll
            for (int i = 0; i < 2; i++)
#pragma unroll
                for (int j = 0; j < 4; j++)
                    acc[i][j] = __builtin_amdgcn_mfma_f32_16x16x32_bf16(a[i], b[j], acc[i][j], 0, 0, 0);
        }
    }
    __syncthreads();   // staging LDS dead; reuse as ytile

    // y = acc + b2 + x  -> ytile
#pragma unroll
    for (int i = 0; i < 2; i++) {
#pragma unroll
        for (int reg = 0; reg < 4; reg++) {
            int rl = wm * 32 + i * 16 + lg * 4 + reg;
            int gr = r0 + rl;
#pragma unroll
            for (int j = 0; j < 4; j++) {
                int gc = wn * 64 + j * 16 + lr;
                float v = acc[i][j][reg] + b2[gc];
                if (gr < NN) v += x[(size_t)gr * 128 + gc];
                ytile[rl * 132 + gc] = v;
            }
        }
    }
    __syncthreads();

    // LayerNorm: 4 threads per row, 32 elems each (strided col = p + 4q)
    int r = tid >> 2, p = tid & 3;
    int gr = r0 + r;
    float sum = 0.f, sq = 0.f;
    float vals[32];
#pragma unroll
    for (int q = 0; q < 32; q++) {
        float v = ytile[r * 132 + p + 4 * q];
        vals[q] = v;
        sum += v;
        sq += v * v;
    }
    sum += __shfl_xor(sum, 1, 64); sq += __shfl_xor(sq, 1, 64);
    sum += __shfl_xor(sum, 2, 64); sq += __shfl_xor(sq, 2, 64);
    float mu = sum * (1.0f / 128.0f);
    float var = sq * (1.0f / 128.0f) - mu * mu;
    float rs = rsqrtf(var + LN_EPS);
    if (gr < NN) {
#pragma unroll
        for (int q = 0; q < 32; q++) {
            int col = p + 4 * q;
            out[(size_t)gr * 128 + col] = (vals[q] - mu) * rs * gamma[col] + beta[col];
        }
    }
}

extern "C" void kernel_launch(void* const* d_in, const int* in_sizes, int n_in,
                              void* d_out, int out_size, void* d_ws, size_t ws_size,
                              hipStream_t stream) {
    const float* x       = (const float*)d_in[0];
    const float* W1      = (const float*)d_in[1];
    const float* b1      = (const float*)d_in[2];
    const float* W2      = (const float*)d_in[3];
    const float* b2      = (const float*)d_in[4];
    const float* gamma   = (const float*)d_in[5];
    const float* beta    = (const float*)d_in[6];
    const int*   ei      = (const int*)d_in[7];
    const float* edist   = (const float*)d_in[8];
    const float* degrees = (const float*)d_in[9];
    float* out = (float*)d_out;

    char* ws = (char*)d_ws;
    size_t off = 0;
    auto alloc = [&](size_t bytes) {
        void* p = ws + off;
        off = (off + bytes + 255) & ~(size_t)255;
        return p;
    };
    int* sorted_dst         = (int*)alloc((size_t)EE * 4);          // 2.56 MB
    int* startA             = (int*)alloc((size_t)NN * 4);
    int* cursor             = (int*)alloc((size_t)NN * 4);
    float* dist             = (float*)alloc((size_t)NN * 4);        // dist_sum -> mean_dist
    int* blocksum           = (int*)alloc(256 * 4);
    int* blockoff           = (int*)alloc(256 * 4);
    unsigned short* featbf  = (unsigned short*)alloc((size_t)NN * 256 * 2);
    unsigned short* W1T     = (unsigned short*)alloc(512 * 256 * 2);
    unsigned short* W2T     = (unsigned short*)alloc(128 * 512 * 2);
    unsigned short* h       = (unsigned short*)alloc((size_t)NN * 512 * 2);

    const int NB = (NN + 255) / 256;   // 196

    hipMemsetAsync(dist, 0, (size_t)NN * 4, stream);
    prep_weights<<<768, 256, 0, stream>>>(W1, W2, W1T, W2T);
    scanA<<<NB, 256, 0, stream>>>(degrees, blocksum);
    scanB<<<1, 256, 0, stream>>>(blocksum, blockoff, NB);
    scanC<<<NB, 256, 0, stream>>>(degrees, blockoff, startA, cursor);
    sort_kernel<<<(EE + 255) / 256, 256, 0, stream>>>(ei, edist, cursor, sorted_dst, dist);
    aggfeat_kernel<<<(NN + 3) / 4, 256, 0, stream>>>(x, startA, degrees, sorted_dst, dist, featbf);
    gemm1_kernel<<<dim3((NN + 63) / 64, 8), 256, 0, stream>>>(featbf, W1T, W1, b1, degrees, dist, h);
    gemm2_ln_kernel<<<(NN + 63) / 64, 256, 0, stream>>>(h, W2T, x, b2, gamma, beta, out);
}

// Round 3
// 299.897 us; speedup vs baseline: 4.5207x; 1.1683x over previous
//
#include <hip/hip_runtime.h>
#include <hip/hip_bf16.h>

#define NN 50000
#define EE 640000
#define LN_EPS 1e-5f

typedef __bf16 bf16x8 __attribute__((ext_vector_type(8)));
typedef float f32x4 __attribute__((ext_vector_type(4)));

static __device__ __forceinline__ unsigned short f2bf(float f) {
    return __builtin_bit_cast(unsigned short, (__bf16)f);
}

// ---- K0: weight prep: W1T[c][k]=bf16(W1[k][c]) (512x256), W2T[c][k]=bf16(W2[k][c]) (128x512),
//          cw[c] = (W1[256][c], W1[257][c], b1[c], 0) packed epilogue constants
__global__ __launch_bounds__(256) void prep_weights(const float* __restrict__ W1,
                                                    const float* __restrict__ W2,
                                                    const float* __restrict__ b1,
                                                    unsigned short* __restrict__ W1T,
                                                    unsigned short* __restrict__ W2T,
                                                    float4* __restrict__ cw) {
    int idx = blockIdx.x * 256 + threadIdx.x;
    if (idx < 131072) {            // 512 cols x 256 k
        int c = idx >> 8, k = idx & 255;
        W1T[idx] = f2bf(W1[k * 512 + c]);
    } else if (idx < 196608) {     // 128 cols x 512 k
        int j = idx - 131072;
        int c = j >> 9, k = j & 511;
        W2T[j] = f2bf(W2[k * 128 + c]);
    } else {                       // 512 packed constants
        int c = idx - 196608;
        cw[c] = make_float4(W1[256 * 512 + c], W1[257 * 512 + c], b1[c], 0.f);
    }
}

// ---- Prefix scan of int(degrees) over NN elements: 3 tiny kernels ----
__global__ __launch_bounds__(256) void scanA(const float* __restrict__ degrees,
                                             int* __restrict__ blocksum) {
    __shared__ int wsum[4];
    int i = blockIdx.x * 256 + threadIdx.x;
    int v = (i < NN) ? (int)(degrees[i] + 0.5f) : 0;
    int s = v;
    for (int d = 1; d < 64; d <<= 1) s += __shfl_xor(s, d, 64);
    if ((threadIdx.x & 63) == 0) wsum[threadIdx.x >> 6] = s;
    __syncthreads();
    if (threadIdx.x == 0) blocksum[blockIdx.x] = wsum[0] + wsum[1] + wsum[2] + wsum[3];
}

__global__ __launch_bounds__(256) void scanB(const int* __restrict__ blocksum,
                                             int* __restrict__ blockoff, int nb) {
    __shared__ int wsum[4];
    int tid = threadIdx.x;
    int v = (tid < nb) ? blocksum[tid] : 0;
    int lane = tid & 63, wid = tid >> 6;
    int inc = v;
    for (int d = 1; d < 64; d <<= 1) { int t = __shfl_up(inc, d, 64); if (lane >= d) inc += t; }
    if (lane == 63) wsum[wid] = inc;
    __syncthreads();
    int add = 0;
    for (int w = 0; w < wid; w++) add += wsum[w];
    inc += add;
    if (tid < nb) blockoff[tid] = inc - v;   // exclusive
}

__global__ __launch_bounds__(256) void scanC(const float* __restrict__ degrees,
                                             const int* __restrict__ blockoff,
                                             int* __restrict__ start,
                                             int* __restrict__ cursor) {
    __shared__ int wsum[4];
    int tid = threadIdx.x;
    int i = blockIdx.x * 256 + tid;
    int v = (i < NN) ? (int)(degrees[i] + 0.5f) : 0;
    int lane = tid & 63, wid = tid >> 6;
    int inc = v;
    for (int d = 1; d < 64; d <<= 1) { int t = __shfl_up(inc, d, 64); if (lane >= d) inc += t; }
    if (lane == 63) wsum[wid] = inc;
    __syncthreads();
    int add = blockoff[blockIdx.x];
    for (int w = 0; w < wid; w++) add += wsum[w];
    int excl = add + inc - v;
    if (i < NN) { start[i] = excl; cursor[i] = excl; }
}

// ---- K_sort: bucket edges by src into CSR order; accumulate dist_sum (small atomics)
__global__ __launch_bounds__(256) void sort_kernel(const int* __restrict__ ei,
                                                   const float* __restrict__ edist,
                                                   int* __restrict__ cursor,
                                                   int* __restrict__ sorted_dst,
                                                   float* __restrict__ dist_sum) {
    int e = blockIdx.x * 256 + threadIdx.x;
    if (e >= EE) return;
    int s = ei[e];
    int d = ei[EE + e];
    int p = atomicAdd(cursor + s, 1);
    sorted_dst[p] = d;
    atomicAdd(dist_sum + s, edist[e]);
}

// ---- K_aggfeat: wave-per-node register aggregation + bf16 feat emit.
__global__ __launch_bounds__(256) void aggfeat_kernel(const float* __restrict__ x,
                                                      const int* __restrict__ start,
                                                      const float* __restrict__ degrees,
                                                      const int* __restrict__ sorted_dst,
                                                      float* __restrict__ dist,
                                                      unsigned short* __restrict__ featbf) {
    int tid = threadIdx.x;
    int node = blockIdx.x * 4 + (tid >> 6);
    int lane = tid & 63;
    if (node >= NN) return;
    int st = start[node];
    int cnt = (int)(degrees[node] + 0.5f);
    float a0 = 0.f, a1 = 0.f;
    for (int base = 0; base < cnt; base += 64) {
        int rem = cnt - base;
        int nv = rem < 64 ? rem : 64;
        int didx = 0;
        if (lane < nv) didx = sorted_dst[st + base + lane];
        int j = 0;
        for (; j + 4 <= nv; j += 4) {
            int d0 = __shfl(didx, j,     64);
            int d1 = __shfl(didx, j + 1, 64);
            int d2 = __shfl(didx, j + 2, 64);
            int d3 = __shfl(didx, j + 3, 64);
            float2 v0 = *((const float2*)(x + (size_t)d0 * 128) + lane);
            float2 v1 = *((const float2*)(x + (size_t)d1 * 128) + lane);
            float2 v2 = *((const float2*)(x + (size_t)d2 * 128) + lane);
            float2 v3 = *((const float2*)(x + (size_t)d3 * 128) + lane);
            a0 += v0.x + v1.x + v2.x + v3.x;
            a1 += v0.y + v1.y + v2.y + v3.y;
        }
        for (; j < nv; j++) {
            int dj = __shfl(didx, j, 64);
            float2 v = *((const float2*)(x + (size_t)dj * 128) + lane);
            a0 += v.x;
            a1 += v.y;
        }
    }
    float degc = fmaxf(degrees[node], 1.0f);
    float inv = 1.0f / degc;
    float2 xv = *((const float2*)(x + (size_t)node * 128) + lane);
    unsigned short o[4] = { f2bf(xv.x), f2bf(xv.y), f2bf(a0 * inv), f2bf(a1 * inv) };
    unsigned short* row = featbf + (size_t)node * 256;
    *(unsigned int*)(row + lane * 2)       = *(unsigned int*)&o[0];
    *(unsigned int*)(row + 128 + lane * 2) = *(unsigned int*)&o[2];
    if (lane == 0) dist[node] = dist[node] * inv;
}

// ---- K_fused: GEMM1(K=256) + relu + GEMM2(K=512) + residual + LayerNorm, one pass.
// Block = 64 rows. A(feat) in registers. Loop ct=0..7 over W1 column tiles of 64:
//   stage B1 (64x256 bf16) + B2 (128x64 bf16 K-slice) -> GEMM1 tile -> epi1 -> per-wave
//   LDS reshape -> GEMM2 partial accumulate. End: +b2 +x, LN, store.
__global__ __launch_bounds__(256) void fused_mlp_ln(const unsigned short* __restrict__ featbf,
                                                    const unsigned short* __restrict__ W1T,
                                                    const unsigned short* __restrict__ W2T,
                                                    const float4* __restrict__ cw,
                                                    const float* __restrict__ x,
                                                    const float* __restrict__ degrees,
                                                    const float* __restrict__ md,
                                                    const float* __restrict__ b2,
                                                    const float* __restrict__ gamma,
                                                    const float* __restrict__ beta,
                                                    float* __restrict__ out) {
    __shared__ __align__(16) unsigned char lds[57344];
    unsigned char* B1 = lds;            // 64 cols x 256 k bf16, swizzled (32KB)
    unsigned char* B2 = lds + 32768;    // 128 cols x 64 k bf16, swizzled (16KB)
    unsigned char* HT = lds + 49152;    // 4 waves x [16][64] bf16 swizzled (8KB)

    int tid = threadIdx.x;
    int wave = tid >> 6, lane = tid & 63;
    int lr = lane & 15, lg = lane >> 4;
    int r0 = blockIdx.x * 64;
    int rowbase = r0 + wave * 16;
    unsigned char* hw = HT + wave * 2048;

    // A fragments: row = lr, k = ks*32 + lg*8
    int gra = rowbase + lr;
    bf16x8 afr[8];
    if (gra < NN) {
        const unsigned char* ap = (const unsigned char*)(featbf + (size_t)gra * 256);
#pragma unroll
        for (int ks = 0; ks < 8; ks++)
            afr[ks] = *(const bf16x8*)(ap + ks * 64 + lg * 16);
    } else {
#pragma unroll
        for (int ks = 0; ks < 8; ks++) afr[ks] = (bf16x8)(__bf16)0.0f;
    }

    // per-lane epilogue-1 row constants: rows m = lg*4 + reg
    float dgv[4], mdv[4];
#pragma unroll
    for (int reg = 0; reg < 4; reg++) {
        int gr = rowbase + lg * 4 + reg;
        dgv[reg] = (gr < NN) ? degrees[gr] : 0.f;
        mdv[reg] = (gr < NN) ? md[gr] : 0.f;
    }

    f32x4 acc2[8] = {};   // D2: row = lg*4+reg, col = j2*16+lr

    for (int ct = 0; ct < 8; ct++) {
        // stage B1 tile (cols ct*64..+64, all K=256)
        const unsigned short* s1 = W1T + (size_t)(ct * 64) * 256;
        for (int idx = tid; idx < 2048; idx += 256) {
            int c = idx >> 5, kslot = idx & 31;
            uint4 v = *(const uint4*)(s1 + c * 256 + kslot * 8);
            *(uint4*)(B1 + (((c << 9) + (kslot << 4)) ^ ((c & 7) << 4))) = v;
        }
        // stage B2 K-slice (all 128 cols, k2 = ct*64..+64)
        for (int idx = tid; idx < 1024; idx += 256) {
            int c = idx >> 3, kslot = idx & 7;
            uint4 v = *(const uint4*)(W2T + (size_t)c * 512 + ct * 64 + kslot * 8);
            *(uint4*)(B2 + (((c << 7) + (kslot << 4)) ^ ((c & 7) << 4))) = v;
        }
        __syncthreads();

        // GEMM1 tile: 64 rows x 64 cols, K=256
        f32x4 acc1[4] = {};
#pragma unroll
        for (int ks = 0; ks < 8; ks++) {
            bf16x8 bf[4];
#pragma unroll
            for (int j = 0; j < 4; j++) {
                int c = j * 16 + lr;
                bf[j] = *(const bf16x8*)(B1 + (((c << 9) + (ks << 6) + (lg << 4)) ^ ((c & 7) << 4)));
            }
#pragma unroll
            for (int j = 0; j < 4; j++)
                acc1[j] = __builtin_amdgcn_mfma_f32_16x16x32_bf16(afr[ks], bf[j], acc1[j], 0, 0, 0);
        }

        // epilogue-1: h = relu(acc1 + dg*wdeg + md*wmd + b1) -> bf16 -> per-wave LDS
#pragma unroll
        for (int j = 0; j < 4; j++) {
            int gc = ct * 64 + j * 16 + lr;
            float4 c4 = cw[gc];
            int cc = j * 16 + lr;
#pragma unroll
            for (int reg = 0; reg < 4; reg++) {
                float v = acc1[j][reg] + dgv[reg] * c4.x + mdv[reg] * c4.y + c4.z;
                v = fmaxf(v, 0.0f);
                int m = lg * 4 + reg;
                *(unsigned short*)(hw + (((m << 7) + cc * 2) ^ ((m & 7) << 4))) = f2bf(v);
            }
        }

        // GEMM2 partial: A2 = h tile (16 rows x 64 k), B2 slice, accumulate acc2
#pragma unroll
        for (int ks2 = 0; ks2 < 2; ks2++) {
            bf16x8 a2 = *(const bf16x8*)(hw + (((lr << 7) + (ks2 << 6) + (lg << 4)) ^ ((lr & 7) << 4)));
#pragma unroll
            for (int j2 = 0; j2 < 8; j2++) {
                int c = j2 * 16 + lr;
                bf16x8 b2f = *(const bf16x8*)(B2 + (((c << 7) + (ks2 << 6) + (lg << 4)) ^ ((c & 7) << 4)));
                acc2[j2] = __builtin_amdgcn_mfma_f32_16x16x32_bf16(a2, b2f, acc2[j2], 0, 0, 0);
            }
        }
        __syncthreads();
    }

    // epilogue-2: y = acc2 + b2 + x; LayerNorm over 128 cols; store.
    float b2v[8], gav[8], bev[8];
#pragma unroll
    for (int j2 = 0; j2 < 8; j2++) {
        int gc = j2 * 16 + lr;
        b2v[j2] = b2[gc];
        gav[j2] = gamma[gc];
        bev[j2] = beta[gc];
    }
    float yv[4][8];
    float sum[4] = {0.f, 0.f, 0.f, 0.f}, sq[4] = {0.f, 0.f, 0.f, 0.f};
#pragma unroll
    for (int reg = 0; reg < 4; reg++) {
        int gr = rowbase + lg * 4 + reg;
        const float* xr = x + (size_t)gr * 128;
#pragma unroll
        for (int j2 = 0; j2 < 8; j2++) {
            float v = acc2[j2][reg] + b2v[j2];
            if (gr < NN) v += xr[j2 * 16 + lr];
            yv[reg][j2] = v;
            sum[reg] += v;
            sq[reg] += v * v;
        }
    }
#pragma unroll
    for (int d = 1; d < 16; d <<= 1) {
#pragma unroll
        for (int reg = 0; reg < 4; reg++) {
            sum[reg] += __shfl_xor(sum[reg], d, 64);
            sq[reg]  += __shfl_xor(sq[reg], d, 64);
        }
    }
#pragma unroll
    for (int reg = 0; reg < 4; reg++) {
        int gr = rowbase + lg * 4 + reg;
        if (gr >= NN) continue;
        float mu = sum[reg] * (1.0f / 128.0f);
        float var = sq[reg] * (1.0f / 128.0f) - mu * mu;
        float rs = rsqrtf(var + LN_EPS);
        float* orow = out + (size_t)gr * 128;
#pragma unroll
        for (int j2 = 0; j2 < 8; j2++)
            orow[j2 * 16 + lr] = (yv[reg][j2] - mu) * rs * gav[j2] + bev[j2];
    }
}

extern "C" void kernel_launch(void* const* d_in, const int* in_sizes, int n_in,
                              void* d_out, int out_size, void* d_ws, size_t ws_size,
                              hipStream_t stream) {
    const float* x       = (const float*)d_in[0];
    const float* W1      = (const float*)d_in[1];
    const float* b1      = (const float*)d_in[2];
    const float* W2      = (const float*)d_in[3];
    const float* b2      = (const float*)d_in[4];
    const float* gamma   = (const float*)d_in[5];
    const float* beta    = (const float*)d_in[6];
    const int*   ei      = (const int*)d_in[7];
    const float* edist   = (const float*)d_in[8];
    const float* degrees = (const float*)d_in[9];
    float* out = (float*)d_out;

    char* ws = (char*)d_ws;
    size_t off = 0;
    auto alloc = [&](size_t bytes) {
        void* p = ws + off;
        off = (off + bytes + 255) & ~(size_t)255;
        return p;
    };
    int* sorted_dst         = (int*)alloc((size_t)EE * 4);
    int* startA             = (int*)alloc((size_t)NN * 4);
    int* cursor             = (int*)alloc((size_t)NN * 4);
    float* dist             = (float*)alloc((size_t)NN * 4);        // dist_sum -> mean_dist
    int* blocksum           = (int*)alloc(256 * 4);
    int* blockoff           = (int*)alloc(256 * 4);
    unsigned short* featbf  = (unsigned short*)alloc((size_t)NN * 256 * 2);
    unsigned short* W1T     = (unsigned short*)alloc(512 * 256 * 2);
    unsigned short* W2T     = (unsigned short*)alloc(128 * 512 * 2);
    float4* cw              = (float4*)alloc(512 * 16);

    const int NB = (NN + 255) / 256;   // 196

    hipMemsetAsync(dist, 0, (size_t)NN * 4, stream);
    prep_weights<<<770, 256, 0, stream>>>(W1, W2, b1, W1T, W2T, cw);
    scanA<<<NB, 256, 0, stream>>>(degrees, blocksum);
    scanB<<<1, 256, 0, stream>>>(blocksum, blockoff, NB);
    scanC<<<NB, 256, 0, stream>>>(degrees, blockoff, startA, cursor);
    sort_kernel<<<(EE + 255) / 256, 256, 0, stream>>>(ei, edist, cursor, sorted_dst, dist);
    aggfeat_kernel<<<(NN + 3) / 4, 256, 0, stream>>>(x, startA, degrees, sorted_dst, dist, featbf);
    fused_mlp_ln<<<(NN + 63) / 64, 256, 0, stream>>>(featbf, W1T, W2T, cw, x, degrees, dist,
                                                     b2, gamma, beta, out);
}

// Round 4
// 253.766 us; speedup vs baseline: 5.3425x; 1.1818x over previous
//
#include <hip/hip_runtime.h>
#include <hip/hip_bf16.h>

#define NN 50000
#define EE 640000
#define LN_EPS 1e-5f
#define KD 272              // extended K (256 feat + deg + md + 1 + 13 zero pad)
#define KB 544              // bytes per feat/W1 row (KD*2)

typedef __bf16 bf16x8 __attribute__((ext_vector_type(8)));
typedef float f32x16 __attribute__((ext_vector_type(16)));

static __device__ __forceinline__ unsigned short f2bf(float f) {
    return __builtin_bit_cast(unsigned short, (__bf16)f);
}
static __device__ __forceinline__ float bflo(unsigned int u) {   // low bf16 of dword
    return __builtin_bit_cast(float, u << 16);
}
static __device__ __forceinline__ float bfhi(unsigned int u) {   // high bf16 of dword
    return __builtin_bit_cast(float, u & 0xffff0000u);
}

// ---- cast x to bf16 (gather source for aggfeat)
__global__ __launch_bounds__(256) void cast_x(const float* __restrict__ x,
                                              unsigned short* __restrict__ xbf) {
    int i = blockIdx.x * 256 + threadIdx.x;          // 8 elems per thread, 3125 blocks exact
    const float4* s = (const float4*)x + (size_t)i * 2;
    float4 a = s[0], b = s[1];
    unsigned short o[8] = { f2bf(a.x), f2bf(a.y), f2bf(a.z), f2bf(a.w),
                            f2bf(b.x), f2bf(b.y), f2bf(b.z), f2bf(b.w) };
    *(uint4*)(xbf + (size_t)i * 8) = *(const uint4*)o;
}

// ---- weight prep: W1Te[c][k] (512 x 272): k<256 = W1[k][c]; 256=W1[256][c]; 257=W1[257][c];
//      258=b1[c]; 259..271=0.  W2T[c][k] (128 x 512) = W2[k][c].
__global__ __launch_bounds__(256) void prep_weights(const float* __restrict__ W1,
                                                    const float* __restrict__ b1,
                                                    const float* __restrict__ W2,
                                                    unsigned short* __restrict__ W1Te,
                                                    unsigned short* __restrict__ W2T) {
    int b = blockIdx.x, tid = threadIdx.x;
    if (b < 512) {
        W1Te[(size_t)b * KD + tid] = f2bf(W1[(size_t)tid * 512 + b]);
        if (tid < 16) {
            float v = 0.f;
            if (tid == 0) v = W1[256 * 512 + b];
            else if (tid == 1) v = W1[257 * 512 + b];
            else if (tid == 2) v = b1[b];
            W1Te[(size_t)b * KD + 256 + tid] = f2bf(v);
        }
    } else {
        int c = b - 512;
        W2T[(size_t)c * 512 + tid]       = f2bf(W2[(size_t)tid * 128 + c]);
        W2T[(size_t)c * 512 + 256 + tid] = f2bf(W2[(size_t)(256 + tid) * 128 + c]);
    }
}

// ---- Prefix scan of int(degrees) over NN elements: 3 tiny kernels ----
__global__ __launch_bounds__(256) void scanA(const float* __restrict__ degrees,
                                             int* __restrict__ blocksum) {
    __shared__ int wsum[4];
    int i = blockIdx.x * 256 + threadIdx.x;
    int v = (i < NN) ? (int)(degrees[i] + 0.5f) : 0;
    int s = v;
    for (int d = 1; d < 64; d <<= 1) s += __shfl_xor(s, d, 64);
    if ((threadIdx.x & 63) == 0) wsum[threadIdx.x >> 6] = s;
    __syncthreads();
    if (threadIdx.x == 0) blocksum[blockIdx.x] = wsum[0] + wsum[1] + wsum[2] + wsum[3];
}

__global__ __launch_bounds__(256) void scanB(const int* __restrict__ blocksum,
                                             int* __restrict__ blockoff, int nb) {
    __shared__ int wsum[4];
    int tid = threadIdx.x;
    int v = (tid < nb) ? blocksum[tid] : 0;
    int lane = tid & 63, wid = tid >> 6;
    int inc = v;
    for (int d = 1; d < 64; d <<= 1) { int t = __shfl_up(inc, d, 64); if (lane >= d) inc += t; }
    if (lane == 63) wsum[wid] = inc;
    __syncthreads();
    int add = 0;
    for (int w = 0; w < wid; w++) add += wsum[w];
    inc += add;
    if (tid < nb) blockoff[tid] = inc - v;   // exclusive
}

__global__ __launch_bounds__(256) void scanC(const float* __restrict__ degrees,
                                             const int* __restrict__ blockoff,
                                             int* __restrict__ start,
                                             int* __restrict__ cursor) {
    __shared__ int wsum[4];
    int tid = threadIdx.x;
    int i = blockIdx.x * 256 + tid;
    int v = (i < NN) ? (int)(degrees[i] + 0.5f) : 0;
    int lane = tid & 63, wid = tid >> 6;
    int inc = v;
    for (int d = 1; d < 64; d <<= 1) { int t = __shfl_up(inc, d, 64); if (lane >= d) inc += t; }
    if (lane == 63) wsum[wid] = inc;
    __syncthreads();
    int add = blockoff[blockIdx.x];
    for (int w = 0; w < wid; w++) add += wsum[w];
    int excl = add + inc - v;
    if (i < NN) { start[i] = excl; cursor[i] = excl; }
}

// ---- bucket edges by src into CSR order; accumulate dist_sum
__global__ __launch_bounds__(256) void sort_kernel(const int* __restrict__ ei,
                                                   const float* __restrict__ edist,
                                                   int* __restrict__ cursor,
                                                   int* __restrict__ sorted_dst,
                                                   float* __restrict__ dist_sum) {
    int e = blockIdx.x * 256 + threadIdx.x;
    if (e >= EE) return;
    int s = ei[e];
    int d = ei[EE + e];
    int p = atomicAdd(cursor + s, 1);
    sorted_dst[p] = d;
    atomicAdd(dist_sum + s, edist[e]);
}

// ---- wave-per-node bf16 gather aggregation + extended feat row emit
// featbf[node][0:128]=bf16(x); [128:256]=bf16(agg/degc); [256]=deg; [257]=mean_dist; [258]=1; rest 0
__global__ __launch_bounds__(256) void aggfeat_kernel(const unsigned short* __restrict__ xbf,
                                                      const int* __restrict__ start,
                                                      const float* __restrict__ degrees,
                                                      const int* __restrict__ sorted_dst,
                                                      const float* __restrict__ dist,
                                                      unsigned short* __restrict__ featbf) {
    int tid = threadIdx.x;
    int node = blockIdx.x * 4 + (tid >> 6);
    int lane = tid & 63;
    if (node >= NN) return;
    int st = start[node];
    int cnt = (int)(degrees[node] + 0.5f);
    float a0 = 0.f, a1 = 0.f;
    for (int base = 0; base < cnt; base += 64) {
        int rem = cnt - base;
        int nv = rem < 64 ? rem : 64;
        int didx = (lane < nv) ? sorted_dst[st + base + lane] : 0;
        int j = 0;
        for (; j + 4 <= nv; j += 4) {
            int d0 = __shfl(didx, j,     64);
            int d1 = __shfl(didx, j + 1, 64);
            int d2 = __shfl(didx, j + 2, 64);
            int d3 = __shfl(didx, j + 3, 64);
            unsigned int v0 = *(const unsigned int*)(xbf + (size_t)d0 * 128 + lane * 2);
            unsigned int v1 = *(const unsigned int*)(xbf + (size_t)d1 * 128 + lane * 2);
            unsigned int v2 = *(const unsigned int*)(xbf + (size_t)d2 * 128 + lane * 2);
            unsigned int v3 = *(const unsigned int*)(xbf + (size_t)d3 * 128 + lane * 2);
            a0 += bflo(v0) + bflo(v1) + bflo(v2) + bflo(v3);
            a1 += bfhi(v0) + bfhi(v1) + bfhi(v2) + bfhi(v3);
        }
        for (; j < nv; j++) {
            int dj = __shfl(didx, j, 64);
            unsigned int v = *(const unsigned int*)(xbf + (size_t)dj * 128 + lane * 2);
            a0 += bflo(v);
            a1 += bfhi(v);
        }
    }
    float degc = fmaxf(degrees[node], 1.0f);
    float inv = 1.0f / degc;
    unsigned short* row = featbf + (size_t)node * KD;
    *(unsigned int*)(row + lane * 2) = *(const unsigned int*)(xbf + (size_t)node * 128 + lane * 2);
    unsigned short o2[2] = { f2bf(a0 * inv), f2bf(a1 * inv) };
    *(unsigned int*)(row + 128 + lane * 2) = *(const unsigned int*)o2;
    if (lane < 4) {
        unsigned short t4[4] = { 0, 0, 0, 0 };
        if (lane == 0) { t4[0] = f2bf(degrees[node]); t4[1] = f2bf(dist[node] * inv); t4[2] = f2bf(1.0f); }
        *(uint2*)(row + 256 + lane * 4) = *(const uint2*)t4;
    }
}

// ---- fused MLP+LN v2: 32x32x16 MFMA, swapped orientation, in-register h hand-off.
// Block = 128 rows, 4 waves x 32 rows. feat (K=272) stationary in registers as B-operand.
// Loop ct=0..7 over 64-col W1 tiles: stage W1/W2 slices -> GEMM1 (W1^T·feat^T) -> relu+pack
// -> shfl_xor(32) k-window assembly -> GEMM2 (W2^T·h^T) accumulate. End: +b2 +x, LN, store.
__global__ __launch_bounds__(256, 2) void fused_mlp_ln(const unsigned short* __restrict__ featbf,
                                                       const unsigned short* __restrict__ W1Te,
                                                       const unsigned short* __restrict__ W2T,
                                                       const float* __restrict__ x,
                                                       const float* __restrict__ b2,
                                                       const float* __restrict__ gamma,
                                                       const float* __restrict__ beta,
                                                       float* __restrict__ out) {
    __shared__ __align__(16) unsigned char lds[34816 + 16384];
    unsigned char* B1 = lds;            // 64 w1cols x 272 k bf16, XOR-swizzled
    unsigned char* B2 = lds + 34816;    // 128 w2cols x 64 k slice bf16, XOR-swizzled

    int tid = threadIdx.x;
    int wave = tid >> 6, lane = tid & 63;
    int ln = lane & 31, hi = lane >> 5;
    int rowbase = blockIdx.x * 128 + wave * 32;
    int gr = rowbase + ln;
    int xorv = (ln & 7) << 4;

    // feat fragments: lane holds feat[gr][k = ks*16 + hi*8 + e]
    bf16x8 ffr[17];
    if (gr < NN) {
        const unsigned char* fp = (const unsigned char*)featbf + (size_t)gr * KB + hi * 16;
#pragma unroll
        for (int ks = 0; ks < 17; ks++)
            ffr[ks] = *(const bf16x8*)(fp + ks * 32);
    } else {
#pragma unroll
        for (int ks = 0; ks < 17; ks++) ffr[ks] = (bf16x8)(__bf16)0.0f;
    }

    f32x16 acc2[4] = {};    // out^T: lane holds out[c][gr], c = at*32 + (reg&3)+8*(reg>>2)+4*hi

    for (int ct = 0; ct < 8; ct++) {
        // stage B1 (64 cols x 272 k) and B2 (128 cols x 64 k slice)
        const unsigned short* s1 = W1Te + (size_t)(ct * 64) * KD;
        for (int i = tid; i < 2048; i += 256) {
            int c = i >> 5, slot = i & 31;
            uint4 v = *(const uint4*)(s1 + c * KD + slot * 8);
            *(uint4*)(B1 + ((c * KB + slot * 16) ^ ((c & 7) << 4))) = v;
        }
        if (tid < 128) {
            int c = tid >> 1, half = tid & 1;
            uint4 v = *(const uint4*)(s1 + c * KD + 256 + half * 8);
            *(uint4*)(B1 + ((c * KB + 512 + half * 16) ^ ((c & 7) << 4))) = v;
        }
        const unsigned short* s2 = W2T + ct * 64;
        for (int i = tid; i < 1024; i += 256) {
            int c = i >> 3, s = i & 7;
            uint4 v = *(const uint4*)(s2 + (size_t)c * 512 + s * 8);
            *(uint4*)(B2 + ((c * 128 + s * 16) ^ ((c & 7) << 4))) = v;
        }
        __syncthreads();

        // GEMM1: D1 = W1tile^T · feat^T  (2 col-tiles x 17 k-steps)
        f32x16 acc1[2] = {};
#pragma unroll
        for (int ks = 0; ks < 17; ks++) {
#pragma unroll
            for (int t = 0; t < 2; t++) {
                int col = t * 32 + ln;
                bf16x8 af = *(const bf16x8*)(B1 + ((col * KB + ks * 32 + hi * 16) ^ xorv));
                acc1[t] = __builtin_amdgcn_mfma_f32_32x32x16_bf16(af, ffr[ks], acc1[t], 0, 0, 0);
            }
        }

        // epilogue-1: relu, pack pairs to bf16 dwords. dw[t][g][i] = h cols {t*32+g*8+4hi+2i, +1}
        unsigned int dw[2][4][2];
#pragma unroll
        for (int t = 0; t < 2; t++)
#pragma unroll
            for (int g = 0; g < 4; g++)
#pragma unroll
                for (int i = 0; i < 2; i++) {
                    float lo = fmaxf(acc1[t][g * 4 + 2 * i], 0.f);
                    float hf = fmaxf(acc1[t][g * 4 + 2 * i + 1], 0.f);
                    dw[t][g][i] = (unsigned int)f2bf(lo) | ((unsigned int)f2bf(hf) << 16);
                }

        // GEMM2: 4 k-windows of 16; B-frag assembled in-register via one lane<->lane^32 exchange
#pragma unroll
        for (int t = 0; t < 2; t++)
#pragma unroll
            for (int w = 0; w < 2; w++) {
                int ks2 = t * 2 + w;
                unsigned int sL0 = dw[t][2 * w][0],     sL1 = dw[t][2 * w][1];
                unsigned int sH0 = dw[t][2 * w + 1][0], sH1 = dw[t][2 * w + 1][1];
                unsigned int send0 = hi ? sL0 : sH0;
                unsigned int send1 = hi ? sL1 : sH1;
                unsigned int r0 = (unsigned int)__shfl_xor((int)send0, 32, 64);
                unsigned int r1 = (unsigned int)__shfl_xor((int)send1, 32, 64);
                uint4 fd;
                fd.x = hi ? r0 : sL0;
                fd.y = hi ? r1 : sL1;
                fd.z = hi ? sH0 : r0;
                fd.w = hi ? sH1 : r1;
                bf16x8 hfr = __builtin_bit_cast(bf16x8, fd);
#pragma unroll
                for (int at = 0; at < 4; at++) {
                    int col2 = at * 32 + ln;
                    bf16x8 a2 = *(const bf16x8*)(B2 + ((col2 * 128 + ks2 * 32 + hi * 16) ^ xorv));
                    acc2[at] = __builtin_amdgcn_mfma_f32_32x32x16_bf16(a2, hfr, acc2[at], 0, 0, 0);
                }
            }
        __syncthreads();
    }

    // epilogue-2: y = out + b2 + x; LayerNorm across the lane pair (l, l^32); store
    bool rok = (gr < NN);
    float sum = 0.f, sq = 0.f;
#pragma unroll
    for (int at = 0; at < 4; at++)
#pragma unroll
        for (int g = 0; g < 4; g++) {
            int c0 = at * 32 + g * 8 + hi * 4;
            float4 bq = *(const float4*)(b2 + c0);
            float4 xq = rok ? *(const float4*)(x + (size_t)gr * 128 + c0) : make_float4(0, 0, 0, 0);
            float vb[4] = { bq.x, bq.y, bq.z, bq.w };
            float vx[4] = { xq.x, xq.y, xq.z, xq.w };
#pragma unroll
            for (int m = 0; m < 4; m++) {
                float v = acc2[at][g * 4 + m] + vb[m] + vx[m];
                acc2[at][g * 4 + m] = v;
                sum += v;
                sq += v * v;
            }
        }
    sum += __shfl_xor(sum, 32, 64);
    sq  += __shfl_xor(sq, 32, 64);
    float mu = sum * (1.0f / 128.0f);
    float var = sq * (1.0f / 128.0f) - mu * mu;
    float rs = rsqrtf(var + LN_EPS);
    if (rok) {
        float* orow = out + (size_t)gr * 128;
#pragma unroll
        for (int at = 0; at < 4; at++)
#pragma unroll
            for (int g = 0; g < 4; g++) {
                int c0 = at * 32 + g * 8 + hi * 4;
                float4 gq = *(const float4*)(gamma + c0);
                float4 be = *(const float4*)(beta + c0);
                float4 o;
                o.x = (acc2[at][g * 4 + 0] - mu) * rs * gq.x + be.x;
                o.y = (acc2[at][g * 4 + 1] - mu) * rs * gq.y + be.y;
                o.z = (acc2[at][g * 4 + 2] - mu) * rs * gq.z + be.z;
                o.w = (acc2[at][g * 4 + 3] - mu) * rs * gq.w + be.w;
                *(float4*)(orow + c0) = o;
            }
    }
}

extern "C" void kernel_launch(void* const* d_in, const int* in_sizes, int n_in,
                              void* d_out, int out_size, void* d_ws, size_t ws_size,
                              hipStream_t stream) {
    const float* x       = (const float*)d_in[0];
    const float* W1      = (const float*)d_in[1];
    const float* b1      = (const float*)d_in[2];
    const float* W2      = (const float*)d_in[3];
    const float* b2      = (const float*)d_in[4];
    const float* gamma   = (const float*)d_in[5];
    const float* beta    = (const float*)d_in[6];
    const int*   ei      = (const int*)d_in[7];
    const float* edist   = (const float*)d_in[8];
    const float* degrees = (const float*)d_in[9];
    float* out = (float*)d_out;

    char* ws = (char*)d_ws;
    size_t off = 0;
    auto alloc = [&](size_t bytes) {
        void* p = ws + off;
        off = (off + bytes + 255) & ~(size_t)255;
        return p;
    };
    int* sorted_dst         = (int*)alloc((size_t)EE * 4);
    int* startA             = (int*)alloc((size_t)NN * 4);
    int* cursor             = (int*)alloc((size_t)NN * 4);
    float* dist             = (float*)alloc((size_t)NN * 4);
    int* blocksum           = (int*)alloc(256 * 4);
    int* blockoff           = (int*)alloc(256 * 4);
    unsigned short* xbf     = (unsigned short*)alloc((size_t)NN * 128 * 2);
    unsigned short* featbf  = (unsigned short*)alloc((size_t)NN * KD * 2);
    unsigned short* W1Te    = (unsigned short*)alloc((size_t)512 * KD * 2);
    unsigned short* W2T     = (unsigned short*)alloc((size_t)128 * 512 * 2);

    const int NB = (NN + 255) / 256;   // 196

    hipMemsetAsync(dist, 0, (size_t)NN * 4, stream);
    cast_x<<<3125, 256, 0, stream>>>(x, xbf);
    prep_weights<<<640, 256, 0, stream>>>(W1, b1, W2, W1Te, W2T);
    scanA<<<NB, 256, 0, stream>>>(degrees, blocksum);
    scanB<<<1, 256, 0, stream>>>(blocksum, blockoff, NB);
    scanC<<<NB, 256, 0, stream>>>(degrees, blockoff, startA, cursor);
    sort_kernel<<<(EE + 255) / 256, 256, 0, stream>>>(ei, edist, cursor, sorted_dst, dist);
    aggfeat_kernel<<<(NN + 3) / 4, 256, 0, stream>>>(xbf, startA, degrees, sorted_dst, dist, featbf);
    fused_mlp_ln<<<(NN + 127) / 128, 256, 0, stream>>>(featbf, W1Te, W2T, x, b2, gamma, beta, out);
}